// Round 9
// baseline (266.866 us; speedup 1.0000x reference)
//
#include <hip/hip_runtime.h>

namespace {

constexpr int kB = 16384;
constexpr int kH = 128;
constexpr int kD = 20;
constexpr int kI = 8;

__device__ __forceinline__ float fexp2(float x) { return __builtin_exp2f(x); }   // v_exp_f32
__device__ __forceinline__ float flog2(float x) { return __builtin_log2f(x); }   // v_log_f32
__device__ __forceinline__ float fexp(float x)  { return __builtin_exp2f(x * 1.4426950408889634f); }

typedef __attribute__((address_space(1))) const void gvoid;
typedef __attribute__((address_space(3))) void lvoid;

__global__ __launch_bounds__(256) void ntm_readhead(
    const float* __restrict__ mem,    // (B,H,D)
    const float* __restrict__ prevw,  // (B,H)
    const float* __restrict__ hid,    // (B,I)
    const float* __restrict__ Wk, const float* __restrict__ bk,
    const float* __restrict__ Wbeta, const float* __restrict__ bbeta,
    const float* __restrict__ Wg, const float* __restrict__ bg,
    const float* __restrict__ Ws, const float* __restrict__ bs,
    float* __restrict__ out_read,     // (B,D)
    float* __restrict__ out_w)        // (B,H)
{
    const int lane = threadIdx.x & 63;
    const int wv   = threadIdx.x >> 6;          // wave index in block (0..3)
    const int row  = (blockIdx.x << 2) + wv;    // one batch row per wave

    __shared__ alignas(16) float mst[4][kH * kD];  // 40 KB: memory[row] staged per wave
    __shared__ alignas(16) float sh2[4][256];      // shift2 per wave
    __shared__ alignas(16) float swg[4][128];      // w_g (later reused for w_next)
    float* mstw = mst[wv];
    float* sh2w = sh2[wv];
    float* swgw = swg[wv];

    // ---- Phase A: DMA memory[row] -> LDS, fire-and-forget (coalesced 1KB/call).
    // LDS dest is wave-uniform base + lane*16; global src is per-lane. Latency
    // hides under ALL of the following compute; drained once before Phase C.
    const float* mrow = mem + (size_t)row * (kH * kD);
    {
        const float4* src4 = reinterpret_cast<const float4*>(mrow);
        #pragma unroll
        for (int t = 0; t < 10; ++t) {
            const float4* gsrc = src4 + (lane + (t << 6));
            float* ldst = mstw + (t << 8);  // uniform across wave
            __builtin_amdgcn_global_load_lds((gvoid*)gsrc, (lvoid*)ldst, 16, 0, 0);
        }
    }

    // ---- hidden state h[8] (wave-uniform broadcast load)
    float h[kI];
    {
        const float4 h0 = *reinterpret_cast<const float4*>(hid + row * kI);
        const float4 h1 = *reinterpret_cast<const float4*>(hid + row * kI + 4);
        h[0]=h0.x; h[1]=h0.y; h[2]=h0.z; h[3]=h0.w;
        h[4]=h1.x; h[5]=h1.y; h[6]=h1.z; h[7]=h1.w;
    }

    const float pw_lo = prevw[row * kH + lane];
    const float pw_hi = prevw[row * kH + lane + 64];

    // ---- scalars beta, g (gamma == g, faithful to reference)
    float beta = bbeta[0], g = bg[0];
    #pragma unroll
    for (int i = 0; i < kI; ++i) {
        beta = fmaf(Wbeta[i], h[i], beta);
        g    = fmaf(Wg[i],    h[i], g);
    }
    const float gamma = g;

    // ---- key vector (D=20), redundant per lane (scalar-load weights, cheap)
    float key[kD];
    #pragma unroll
    for (int d = 0; d < kD; ++d) {
        float a = bk[d];
        #pragma unroll
        for (int i = 0; i < kI; ++i) a = fmaf(Wk[d * kI + i], h[i], a);
        key[d] = fmaxf(a, 0.0f);
    }

    // ---- cos = key . memory[B-1][h']   (memory[-1] slice is L1/L2-hot, 10 KB)
    const float* Ml = mem + (size_t)(kB - 1) * (kH * kD);
    float c_lo = 0.0f, c_hi = 0.0f;
    #pragma unroll
    for (int k = 0; k < 5; ++k) {
        const float4 alo = *reinterpret_cast<const float4*>(Ml + lane * kD + 4 * k);
        const float4 ahi = *reinterpret_cast<const float4*>(Ml + (lane + 64) * kD + 4 * k);
        c_lo = fmaf(alo.x, key[4*k+0], c_lo); c_lo = fmaf(alo.y, key[4*k+1], c_lo);
        c_lo = fmaf(alo.z, key[4*k+2], c_lo); c_lo = fmaf(alo.w, key[4*k+3], c_lo);
        c_hi = fmaf(ahi.x, key[4*k+0], c_hi); c_hi = fmaf(ahi.y, key[4*k+1], c_hi);
        c_hi = fmaf(ahi.z, key[4*k+2], c_hi); c_hi = fmaf(ahi.w, key[4*k+3], c_hi);
    }

    // ---- content softmax over H (2 elems/lane + 6-step butterfly)
    float s_lo = c_lo * beta, s_hi = c_hi * beta;
    float mx = fmaxf(s_lo, s_hi);
    #pragma unroll
    for (int o = 32; o > 0; o >>= 1) mx = fmaxf(mx, __shfl_xor(mx, o));
    float e_lo = fexp(s_lo - mx), e_hi = fexp(s_hi - mx);
    float es = e_lo + e_hi;
    #pragma unroll
    for (int o = 32; o > 0; o >>= 1) es += __shfl_xor(es, o);
    const float einv = 1.0f / es;

    // ---- gate: w_g = g*w_content + (1-g)*prev
    const float wc_lo = e_lo * einv, wc_hi = e_hi * einv;
    const float wg_lo = fmaf(g, wc_lo - pw_lo, pw_lo);
    const float wg_hi = fmaf(g, wc_hi - pw_hi, pw_hi);
    swgw[lane]      = wg_lo;
    swgw[lane + 64] = wg_hi;

    // ---- shift softmax
    float l_lo = bs[lane], l_hi = bs[lane + 64];
    {
        const float4 a0 = *reinterpret_cast<const float4*>(Ws + lane * kI);
        const float4 a1 = *reinterpret_cast<const float4*>(Ws + lane * kI + 4);
        const float4 b0 = *reinterpret_cast<const float4*>(Ws + (lane + 64) * kI);
        const float4 b1 = *reinterpret_cast<const float4*>(Ws + (lane + 64) * kI + 4);
        l_lo = fmaf(a0.x,h[0], l_lo); l_lo = fmaf(a0.y,h[1], l_lo);
        l_lo = fmaf(a0.z,h[2], l_lo); l_lo = fmaf(a0.w,h[3], l_lo);
        l_lo = fmaf(a1.x,h[4], l_lo); l_lo = fmaf(a1.y,h[5], l_lo);
        l_lo = fmaf(a1.z,h[6], l_lo); l_lo = fmaf(a1.w,h[7], l_lo);
        l_hi = fmaf(b0.x,h[0], l_hi); l_hi = fmaf(b0.y,h[1], l_hi);
        l_hi = fmaf(b0.z,h[2], l_hi); l_hi = fmaf(b0.w,h[3], l_hi);
        l_hi = fmaf(b1.x,h[4], l_hi); l_hi = fmaf(b1.y,h[5], l_hi);
        l_hi = fmaf(b1.z,h[6], l_hi); l_hi = fmaf(b1.w,h[7], l_hi);
    }
    float mx2 = fmaxf(l_lo, l_hi);
    #pragma unroll
    for (int o = 32; o > 0; o >>= 1) mx2 = fmaxf(mx2, __shfl_xor(mx2, o));
    float e2_lo = fexp(l_lo - mx2), e2_hi = fexp(l_hi - mx2);
    float es2 = e2_lo + e2_hi;
    #pragma unroll
    for (int o = 32; o > 0; o >>= 1) es2 += __shfl_xor(es2, o);
    const float inv2 = 1.0f / es2;
    const float sf_lo = e2_lo * inv2, sf_hi = e2_hi * inv2;

    // ---- build shift2[k] = shift[(k+1) & 127], k in [0,255]
    // (offset chosen so conv float4 reads land 16B-aligned)
    sh2w[(lane + 127) & 127] = sf_lo;   // k = lane-1 mod 128
    sh2w[lane + 127]         = sf_lo;
    sh2w[lane + 63]          = sf_hi;   // k = lane+64-1
    sh2w[lane + 191]         = sf_hi;
    if (lane == 0) sh2w[255] = sf_lo;   // shift[0]

    // ---- circular conv: circ[i] = sum_j shift[(i-j)%128] * w_g[j]
    // lane = (q, jh): i-quad i0=4q, j-half jh. Rolling 8-float window:
    // step t uses words [w0, w0+7] of shift2, w0 = i0 - j0 + 124, j0 -= 4 each step.
    const int q  = lane & 31;
    const int jh = lane >> 5;
    const int i0 = q << 2;
    int j0 = jh ? 124 : 60;
    int w0 = i0 - j0 + 124;
    float4 qlo = *reinterpret_cast<const float4*>(&sh2w[w0]);
    float c0 = 0.f, c1 = 0.f, c2 = 0.f, c3 = 0.f;
    #pragma unroll 4
    for (int t = 0; t < 16; ++t) {
        const float4 qhi = *reinterpret_cast<const float4*>(&sh2w[w0 + 4]);
        const float4 wg4 = *reinterpret_cast<const float4*>(&swgw[j0]);
        // c[r] += wg4[jc] * W[3 + r - jc], W = {qlo.xyzw, qhi.xyz}
        c0 = fmaf(wg4.x, qlo.w, c0); c0 = fmaf(wg4.y, qlo.z, c0);
        c0 = fmaf(wg4.z, qlo.y, c0); c0 = fmaf(wg4.w, qlo.x, c0);
        c1 = fmaf(wg4.x, qhi.x, c1); c1 = fmaf(wg4.y, qlo.w, c1);
        c1 = fmaf(wg4.z, qlo.z, c1); c1 = fmaf(wg4.w, qlo.y, c1);
        c2 = fmaf(wg4.x, qhi.y, c2); c2 = fmaf(wg4.y, qhi.x, c2);
        c2 = fmaf(wg4.z, qlo.w, c2); c2 = fmaf(wg4.w, qlo.z, c2);
        c3 = fmaf(wg4.x, qhi.z, c3); c3 = fmaf(wg4.y, qhi.y, c3);
        c3 = fmaf(wg4.z, qhi.x, c3); c3 = fmaf(wg4.w, qlo.w, c3);
        qlo = qhi; w0 += 4; j0 -= 4;
    }
    // combine the two j-halves
    c0 += __shfl_xor(c0, 32); c1 += __shfl_xor(c1, 32);
    c2 += __shfl_xor(c2, 32); c3 += __shfl_xor(c3, 32);

    // ---- sharpen: w_pow = circ ** gamma (circ > 0 guaranteed), normalize
    const float p0 = fexp2(gamma * flog2(c0));
    const float p1 = fexp2(gamma * flog2(c1));
    const float p2 = fexp2(gamma * flog2(c2));
    const float p3 = fexp2(gamma * flog2(c3));
    float ps = (p0 + p1) + (p2 + p3);
    #pragma unroll
    for (int o = 16; o > 0; o >>= 1) ps += __shfl_xor(ps, o);  // halves are duplicates
    const float pinv = 1.0f / ps;
    const float wn0 = p0 * pinv, wn1 = p1 * pinv, wn2 = p2 * pinv, wn3 = p3 * pinv;

    // ---- store w_next + stash to LDS for canonical (lane, lane+64) layout
    if (jh == 0) {
        *reinterpret_cast<float4*>(out_w + (size_t)row * kH + i0) = make_float4(wn0, wn1, wn2, wn3);
        *reinterpret_cast<float4*>(&swgw[i0]) = make_float4(wn0, wn1, wn2, wn3);
    }
    const float wn_lo = swgw[lane];
    const float wn_hi = swgw[lane + 64];

    // ---- Phase C: drain the DMA, then read = w_next . memory[row] from LDS
    asm volatile("s_waitcnt vmcnt(0)" ::: "memory");
    const float4* mlo4 = reinterpret_cast<const float4*>(mstw + kD * lane);        // 16B aligned
    const float4* mhi4 = reinterpret_cast<const float4*>(mstw + kD * (lane + 64));
    float acc[kD];
    #pragma unroll
    for (int k = 0; k < 5; ++k) {
        const float4 a = mlo4[k];
        const float4 b = mhi4[k];
        acc[4*k+0] = fmaf(wn_lo, a.x, wn_hi * b.x);
        acc[4*k+1] = fmaf(wn_lo, a.y, wn_hi * b.y);
        acc[4*k+2] = fmaf(wn_lo, a.z, wn_hi * b.z);
        acc[4*k+3] = fmaf(wn_lo, a.w, wn_hi * b.w);
    }
    #pragma unroll
    for (int o = 32; o > 0; o >>= 1) {
        #pragma unroll
        for (int d = 0; d < kD; ++d) acc[d] += __shfl_xor(acc[d], o);
    }
    if (lane < kD) {
        float outv = acc[0];
        #pragma unroll
        for (int d = 1; d < kD; ++d) if (lane == d) outv = acc[d];  // static indices only
        out_read[(size_t)row * kD + lane] = outv;
    }
}

}  // namespace

extern "C" void kernel_launch(void* const* d_in, const int* in_sizes, int n_in,
                              void* d_out, int out_size, void* d_ws, size_t ws_size,
                              hipStream_t stream) {
    const float* mem   = (const float*)d_in[0];
    const float* prevw = (const float*)d_in[1];
    const float* hid   = (const float*)d_in[2];
    const float* Wk    = (const float*)d_in[3];
    const float* bk    = (const float*)d_in[4];
    const float* Wbeta = (const float*)d_in[5];
    const float* bbeta = (const float*)d_in[6];
    const float* Wg    = (const float*)d_in[7];
    const float* bg    = (const float*)d_in[8];
    const float* Ws_   = (const float*)d_in[9];
    const float* bs    = (const float*)d_in[10];

    float* out_read = (float*)d_out;                       // (B,D) first
    float* out_w    = (float*)d_out + (size_t)kB * kD;     // then (B,H)

    dim3 grid(kB / 4), block(256);  // one wave per batch row
    hipLaunchKernelGGL(ntm_readhead, grid, block, 0, stream,
                       mem, prevw, hid, Wk, bk, Wbeta, bbeta, Wg, bg, Ws_, bs,
                       out_read, out_w);
}

// Round 11
// 260.484 us; speedup vs baseline: 1.0245x; 1.0245x over previous
//
#include <hip/hip_runtime.h>

namespace {

constexpr int kB = 16384;
constexpr int kH = 128;
constexpr int kD = 20;
constexpr int kI = 8;

__device__ __forceinline__ float fexp2(float x) { return __builtin_exp2f(x); }   // v_exp_f32
__device__ __forceinline__ float flog2(float x) { return __builtin_log2f(x); }   // v_log_f32
__device__ __forceinline__ float fexp(float x)  { return __builtin_exp2f(x * 1.4426950408889634f); }

typedef __attribute__((address_space(1))) const void gvoid;
typedef __attribute__((address_space(3))) void lvoid;

__global__ __launch_bounds__(256) void ntm_readhead(
    const float* __restrict__ mem,    // (B,H,D)
    const float* __restrict__ prevw,  // (B,H)
    const float* __restrict__ hid,    // (B,I)
    const float* __restrict__ Wk, const float* __restrict__ bk,
    const float* __restrict__ Wbeta, const float* __restrict__ bbeta,
    const float* __restrict__ Wg, const float* __restrict__ bg,
    const float* __restrict__ Ws, const float* __restrict__ bs,
    float* __restrict__ out_read,     // (B,D)
    float* __restrict__ out_w)        // (B,H)
{
    const int lane = threadIdx.x & 63;
    const int wv   = threadIdx.x >> 6;          // wave index in block (0..3)
    const int row  = (blockIdx.x << 2) + wv;    // one batch row per wave

    __shared__ alignas(16) float mls[kH * kD];  // 10 KB: memory[-1], BLOCK-shared
    __shared__ alignas(16) float sh2[4][256];   // shift2 per wave
    __shared__ alignas(16) float swg[4][128];   // w_g (later reused for w_next)
    float* sh2w = sh2[wv];
    float* swgw = swg[wv];

    // ---- Phase 0: coalesced DMA of memory[-1] (10 KB) into block-shared LDS.
    // 10 x 1KB calls split across the 4 waves; one barrier; all waves then read
    // their cos rows from LDS instead of 80B-stride global scatter.
    {
        const float4* Ml4 = reinterpret_cast<const float4*>(mem + (size_t)(kB - 1) * (kH * kD));
        for (int t = wv; t < 10; t += 4) {      // wave-uniform trip count
            __builtin_amdgcn_global_load_lds((gvoid*)(Ml4 + lane + (t << 6)),
                                             (lvoid*)(mls + (t << 8)), 16, 0, 0);
        }
        asm volatile("s_waitcnt vmcnt(0)" ::: "memory");
        __syncthreads();
    }

    // ---- hidden state h[8] (wave-uniform broadcast load)
    float h[kI];
    {
        const float4 h0 = *reinterpret_cast<const float4*>(hid + row * kI);
        const float4 h1 = *reinterpret_cast<const float4*>(hid + row * kI + 4);
        h[0]=h0.x; h[1]=h0.y; h[2]=h0.z; h[3]=h0.w;
        h[4]=h1.x; h[5]=h1.y; h[6]=h1.z; h[7]=h1.w;
    }

    // ---- issue the bulk memory[row] loads EARLY (latency hides under compute)
    // R3 register path: proven equal to DMA staging, keeps LDS small.
    const float* mrow = mem + (size_t)row * (kH * kD);
    float4 mlo[5], mhi[5];
    #pragma unroll
    for (int k = 0; k < 5; ++k) {
        mlo[k] = *reinterpret_cast<const float4*>(mrow + lane * kD + 4 * k);
        mhi[k] = *reinterpret_cast<const float4*>(mrow + (lane + 64) * kD + 4 * k);
    }
    const float pw_lo = prevw[row * kH + lane];
    const float pw_hi = prevw[row * kH + lane + 64];

    // ---- scalars beta, g (gamma == g, faithful to reference)
    float beta = bbeta[0], g = bg[0];
    #pragma unroll
    for (int i = 0; i < kI; ++i) {
        beta = fmaf(Wbeta[i], h[i], beta);
        g    = fmaf(Wg[i],    h[i], g);
    }
    const float gamma = g;

    // ---- key vector (D=20), redundant per lane (scalar-load weights, cheap)
    float key[kD];
    #pragma unroll
    for (int d = 0; d < kD; ++d) {
        float a = bk[d];
        #pragma unroll
        for (int i = 0; i < kI; ++i) a = fmaf(Wk[d * kI + i], h[i], a);
        key[d] = fmaxf(a, 0.0f);
    }

    // ---- cos = key . memory[-1][h']  (from LDS; 5x ds_read_b128 per row)
    float c_lo = 0.0f, c_hi = 0.0f;
    {
        const float4* a4 = reinterpret_cast<const float4*>(mls + kD * lane);         // 80B-aligned
        const float4* b4 = reinterpret_cast<const float4*>(mls + kD * (lane + 64));
        #pragma unroll
        for (int k = 0; k < 5; ++k) {
            const float4 alo = a4[k];
            const float4 ahi = b4[k];
            c_lo = fmaf(alo.x, key[4*k+0], c_lo); c_lo = fmaf(alo.y, key[4*k+1], c_lo);
            c_lo = fmaf(alo.z, key[4*k+2], c_lo); c_lo = fmaf(alo.w, key[4*k+3], c_lo);
            c_hi = fmaf(ahi.x, key[4*k+0], c_hi); c_hi = fmaf(ahi.y, key[4*k+1], c_hi);
            c_hi = fmaf(ahi.z, key[4*k+2], c_hi); c_hi = fmaf(ahi.w, key[4*k+3], c_hi);
        }
    }

    // ---- content softmax over H (2 elems/lane + 6-step butterfly)
    float s_lo = c_lo * beta, s_hi = c_hi * beta;
    float mx = fmaxf(s_lo, s_hi);
    #pragma unroll
    for (int o = 32; o > 0; o >>= 1) mx = fmaxf(mx, __shfl_xor(mx, o));
    float e_lo = fexp(s_lo - mx), e_hi = fexp(s_hi - mx);
    float es = e_lo + e_hi;
    #pragma unroll
    for (int o = 32; o > 0; o >>= 1) es += __shfl_xor(es, o);
    const float einv = 1.0f / es;

    // ---- gate: w_g = g*w_content + (1-g)*prev
    const float wc_lo = e_lo * einv, wc_hi = e_hi * einv;
    const float wg_lo = fmaf(g, wc_lo - pw_lo, pw_lo);
    const float wg_hi = fmaf(g, wc_hi - pw_hi, pw_hi);
    swgw[lane]      = wg_lo;
    swgw[lane + 64] = wg_hi;

    // ---- shift softmax
    float l_lo = bs[lane], l_hi = bs[lane + 64];
    {
        const float4 a0 = *reinterpret_cast<const float4*>(Ws + lane * kI);
        const float4 a1 = *reinterpret_cast<const float4*>(Ws + lane * kI + 4);
        const float4 b0 = *reinterpret_cast<const float4*>(Ws + (lane + 64) * kI);
        const float4 b1 = *reinterpret_cast<const float4*>(Ws + (lane + 64) * kI + 4);
        l_lo = fmaf(a0.x,h[0], l_lo); l_lo = fmaf(a0.y,h[1], l_lo);
        l_lo = fmaf(a0.z,h[2], l_lo); l_lo = fmaf(a0.w,h[3], l_lo);
        l_lo = fmaf(a1.x,h[4], l_lo); l_lo = fmaf(a1.y,h[5], l_lo);
        l_lo = fmaf(a1.z,h[6], l_lo); l_lo = fmaf(a1.w,h[7], l_lo);
        l_hi = fmaf(b0.x,h[0], l_hi); l_hi = fmaf(b0.y,h[1], l_hi);
        l_hi = fmaf(b0.z,h[2], l_hi); l_hi = fmaf(b0.w,h[3], l_hi);
        l_hi = fmaf(b1.x,h[4], l_hi); l_hi = fmaf(b1.y,h[5], l_hi);
        l_hi = fmaf(b1.z,h[6], l_hi); l_hi = fmaf(b1.w,h[7], l_hi);
    }
    float mx2 = fmaxf(l_lo, l_hi);
    #pragma unroll
    for (int o = 32; o > 0; o >>= 1) mx2 = fmaxf(mx2, __shfl_xor(mx2, o));
    float e2_lo = fexp(l_lo - mx2), e2_hi = fexp(l_hi - mx2);
    float es2 = e2_lo + e2_hi;
    #pragma unroll
    for (int o = 32; o > 0; o >>= 1) es2 += __shfl_xor(es2, o);
    const float inv2 = 1.0f / es2;
    const float sf_lo = e2_lo * inv2, sf_hi = e2_hi * inv2;

    // ---- build shift2[k] = shift[(k+1) & 127], k in [0,255]
    // (offset chosen so conv float4 reads land 16B-aligned)
    sh2w[(lane + 127) & 127] = sf_lo;   // k = lane-1 mod 128
    sh2w[lane + 127]         = sf_lo;
    sh2w[lane + 63]          = sf_hi;   // k = lane+64-1
    sh2w[lane + 191]         = sf_hi;
    if (lane == 0) sh2w[255] = sf_lo;   // shift[0]

    // ---- circular conv: circ[i] = sum_j shift[(i-j)%128] * w_g[j]
    // lane = (q, jh): i-quad i0=4q, j-half jh. Rolling 8-float window:
    // step t uses words [w0, w0+7] of shift2, w0 = i0 - j0 + 124, j0 -= 4 each step.
    const int q  = lane & 31;
    const int jh = lane >> 5;
    const int i0 = q << 2;
    int j0 = jh ? 124 : 60;
    int w0 = i0 - j0 + 124;
    float4 qlo = *reinterpret_cast<const float4*>(&sh2w[w0]);
    float c0 = 0.f, c1 = 0.f, c2 = 0.f, c3 = 0.f;
    #pragma unroll 4
    for (int t = 0; t < 16; ++t) {
        const float4 qhi = *reinterpret_cast<const float4*>(&sh2w[w0 + 4]);
        const float4 wg4 = *reinterpret_cast<const float4*>(&swgw[j0]);
        // c[r] += wg4[jc] * W[3 + r - jc], W = {qlo.xyzw, qhi.xyz}
        c0 = fmaf(wg4.x, qlo.w, c0); c0 = fmaf(wg4.y, qlo.z, c0);
        c0 = fmaf(wg4.z, qlo.y, c0); c0 = fmaf(wg4.w, qlo.x, c0);
        c1 = fmaf(wg4.x, qhi.x, c1); c1 = fmaf(wg4.y, qlo.w, c1);
        c1 = fmaf(wg4.z, qlo.z, c1); c1 = fmaf(wg4.w, qlo.y, c1);
        c2 = fmaf(wg4.x, qhi.y, c2); c2 = fmaf(wg4.y, qhi.x, c2);
        c2 = fmaf(wg4.z, qlo.w, c2); c2 = fmaf(wg4.w, qlo.z, c2);
        c3 = fmaf(wg4.x, qhi.z, c3); c3 = fmaf(wg4.y, qhi.y, c3);
        c3 = fmaf(wg4.z, qhi.x, c3); c3 = fmaf(wg4.w, qlo.w, c3);
        qlo = qhi; w0 += 4; j0 -= 4;
    }
    // combine the two j-halves
    c0 += __shfl_xor(c0, 32); c1 += __shfl_xor(c1, 32);
    c2 += __shfl_xor(c2, 32); c3 += __shfl_xor(c3, 32);

    // ---- sharpen: w_pow = circ ** gamma (circ > 0 guaranteed), normalize
    const float p0 = fexp2(gamma * flog2(c0));
    const float p1 = fexp2(gamma * flog2(c1));
    const float p2 = fexp2(gamma * flog2(c2));
    const float p3 = fexp2(gamma * flog2(c3));
    float ps = (p0 + p1) + (p2 + p3);
    #pragma unroll
    for (int o = 16; o > 0; o >>= 1) ps += __shfl_xor(ps, o);  // halves are duplicates
    const float pinv = 1.0f / ps;
    const float wn0 = p0 * pinv, wn1 = p1 * pinv, wn2 = p2 * pinv, wn3 = p3 * pinv;

    // ---- store w_next + stash to LDS for canonical (lane, lane+64) layout
    if (jh == 0) {
        *reinterpret_cast<float4*>(out_w + (size_t)row * kH + i0) = make_float4(wn0, wn1, wn2, wn3);
        *reinterpret_cast<float4*>(&swgw[i0]) = make_float4(wn0, wn1, wn2, wn3);
    }
    const float wn_lo = swgw[lane];
    const float wn_hi = swgw[lane + 64];

    // ---- read = w_next . memory[row]  (from registers, R3 path)
    float acc[kD];
    #pragma unroll
    for (int k = 0; k < 5; ++k) {
        acc[4*k+0] = fmaf(wn_lo, mlo[k].x, wn_hi * mhi[k].x);
        acc[4*k+1] = fmaf(wn_lo, mlo[k].y, wn_hi * mhi[k].y);
        acc[4*k+2] = fmaf(wn_lo, mlo[k].z, wn_hi * mhi[k].z);
        acc[4*k+3] = fmaf(wn_lo, mlo[k].w, wn_hi * mhi[k].w);
    }
    #pragma unroll
    for (int o = 32; o > 0; o >>= 1) {
        #pragma unroll
        for (int d = 0; d < kD; ++d) acc[d] += __shfl_xor(acc[d], o);
    }
    if (lane < kD) {
        float outv = acc[0];
        #pragma unroll
        for (int d = 1; d < kD; ++d) if (lane == d) outv = acc[d];  // static indices only
        out_read[(size_t)row * kD + lane] = outv;
    }
}

}  // namespace

extern "C" void kernel_launch(void* const* d_in, const int* in_sizes, int n_in,
                              void* d_out, int out_size, void* d_ws, size_t ws_size,
                              hipStream_t stream) {
    const float* mem   = (const float*)d_in[0];
    const float* prevw = (const float*)d_in[1];
    const float* hid   = (const float*)d_in[2];
    const float* Wk    = (const float*)d_in[3];
    const float* bk    = (const float*)d_in[4];
    const float* Wbeta = (const float*)d_in[5];
    const float* bbeta = (const float*)d_in[6];
    const float* Wg    = (const float*)d_in[7];
    const float* bg    = (const float*)d_in[8];
    const float* Ws_   = (const float*)d_in[9];
    const float* bs    = (const float*)d_in[10];

    float* out_read = (float*)d_out;                       // (B,D) first
    float* out_w    = (float*)d_out + (size_t)kB * kD;     // then (B,H)

    dim3 grid(kB / 4), block(256);  // one wave per batch row
    hipLaunchKernelGGL(ntm_readhead, grid, block, 0, stream,
                       mem, prevw, hid, Wk, bk, Wbeta, bbeta, Wg, bg, Ws_, bs,
                       out_read, out_w);
}